// Round 6
// baseline (468.771 us; speedup 1.0000x reference)
//
#include <hip/hip_runtime.h>
#include <math.h>

#define W 512
#define H 512
#define S (W * H)        // 262144
#define B 8
#define NIMG 16
#define CORE 64
#define HALO 12
#define LDT 88           // tile width / row stride
#define LROWS 90         // 88 rows + 2 pad rows (register-window overread)
#define NQ 22            // quads per tile row
#define FINF __builtin_huge_valf()

__device__ __forceinline__ float4 ld4s(const float* p) { return *(const float4*)p; }
__device__ __forceinline__ void st4s(float* p, float4 v) { *(float4*)p = v; }

// block-wide float sum over 256 threads; result valid in thread 0.
__device__ __forceinline__ float blockReduce(float v, float* sw) {
    #pragma unroll
    for (int o = 32; o; o >>= 1) v += __shfl_down(v, o, 64);
    int lane = threadIdx.x & 63, wid = threadIdx.x >> 6;
    if (lane == 0) sw[wid] = v;
    __syncthreads();
    float r = (threadIdx.x < 4) ? sw[threadIdx.x] : 0.f;
    if (wid == 0) { r += __shfl_down(r, 2, 64); r += __shfl_down(r, 1, 64); }
    __syncthreads();
    return r;
}

// ---------------------------------------------------------------- phase 1
// softmax fg prob + y cast -> J0; dice partials -> pb; block 0 zeros acc.
__global__ __launch_bounds__(256) void phase1_kernel(
        const float* __restrict__ net, const int* __restrict__ yt,
        float* __restrict__ J0, double* __restrict__ pb,
        double* __restrict__ acc) {
    __shared__ float sw[4];
    const int tid = threadIdx.x;
    if (blockIdx.x == 0 && tid < 48) acc[tid] = 0.0;   // endpoint accumulators
    float inter = 0.f, sp = 0.f, sy = 0.f;
    for (int i = blockIdx.x * 256 + tid; i < B * S / 4; i += 1024 * 256) {
        int b = i >> 16;               // S/4 = 65536 quads per image
        int s = (i & 65535) << 2;
        const float* nb = net + (size_t)b * 2 * S;
        float4 x0 = ld4s(nb + s);
        float4 x1 = ld4s(nb + S + s);
        int4 yv = *(const int4*)(yt + (size_t)b * S + s);
        float4 p, yf;
        p.x = 1.f / (1.f + expf(x0.x - x1.x));
        p.y = 1.f / (1.f + expf(x0.y - x1.y));
        p.z = 1.f / (1.f + expf(x0.z - x1.z));
        p.w = 1.f / (1.f + expf(x0.w - x1.w));
        yf.x = (float)yv.x; yf.y = (float)yv.y; yf.z = (float)yv.z; yf.w = (float)yv.w;
        st4s(J0 + (size_t)b * S + s, p);
        st4s(J0 + (size_t)(B + b) * S + s, yf);
        inter += p.x * yf.x + p.y * yf.y + p.z * yf.z + p.w * yf.w;
        sp += p.x + p.y + p.z + p.w;
        sy += yf.x + yf.y + yf.z + yf.w;
    }
    float v;
    v = blockReduce(inter, sw); if (tid == 0) pb[blockIdx.x * 3 + 0] = (double)v;
    v = blockReduce(sp, sw);    if (tid == 0) pb[blockIdx.x * 3 + 1] = (double)v;
    v = blockReduce(sy, sw);    if (tid == 0) pb[blockIdx.x * 3 + 2] = (double)v;
}

// ---------------------------------------------------------------- fused skeleton
// T=6 rounds per launch, 88x88 logical tile, SINGLE 90x88 LDS buffer (31.7 KB)
// updated in place. launch_bounds(512,8) -> VGPR<=64 -> 4 blocks/CU: all 1024
// blocks co-resident, no block tail (r5 had 3/CU + 25% tail).
// Carry trick: dilate's "old J core rows" = previous round's E[1],E[2] ->
// carried in registers (Jc0/Jc1); only round r0 reads the stash from LDS.
template <bool INIT>
__global__ __launch_bounds__(512, 8) void skel_fused_kernel(
        const float* __restrict__ Jin, float* __restrict__ Jout,
        float* __restrict__ skel, int r0) {
    __shared__ float Jl[LROWS * LDT];   // 90 x 88 floats = 31680 B
    const int tid = threadIdx.x;
    const int lane = tid & 63;
    const int img = blockIdx.x >> 6;
    const int t64 = blockIdx.x & 63;
    const int ty = t64 >> 3, tx = t64 & 7;
    const int y0 = ty * CORE - HALO, x0 = tx * CORE - HALO;
    const float* Ji = Jin + (size_t)img * S;
    float* Jo = Jout + (size_t)img * S;
    float* Sk = skel + (size_t)img * S;
    const bool interior = (ty > 0) & (ty < 7) & (tx > 0) & (tx < 7);

    // ---- load 88x88 J tile (quads all-in/out in x: x0 % 4 == 0)
    if (interior) {
        for (int i = tid; i < LDT * LDT / 4; i += 512) {
            int r = i / NQ, q = i - (i / NQ) * NQ;
            st4s(&Jl[r * LDT + (q << 2)],
                 ld4s(Ji + (y0 + r) * W + x0 + (q << 2)));
        }
    } else {
        for (int i = tid; i < LDT * LDT / 4; i += 512) {
            int r = i / NQ, q = i - (i / NQ) * NQ;
            int gy = y0 + r, gx = x0 + (q << 2);
            float4 v;
            if ((unsigned)gy < H && (unsigned)gx < W) v = ld4s(Ji + gy * W + gx);
            else v = make_float4(FINF, FINF, FINF, FINF);
            st4s(&Jl[r * LDT + (q << 2)], v);
        }
    }

    // ---- skel in registers: thread = 2-row core slab, rows {2ss,2ss+1}, quad sq
    const int sq = tid & 15, ss = tid >> 4;     // sq 0..15, ss 0..31
    const int tcol = HALO + (sq << 2);          // tile col of core quad
    const int gxc = tx * CORE + (sq << 2);      // global col of core quad
    const int row0 = ss << 1;                   // core row offset of slab
    float4 sk2[2];
    #pragma unroll
    for (int j = 0; j < 2; ++j) {
        if (INIT) sk2[j] = make_float4(0.f, 0.f, 0.f, 0.f);
        else      sk2[j] = ld4s(Sk + (ty * CORE + row0 + j) * W + gxc);
    }
    __syncthreads();

    float4 Jc0, Jc1;   // carried old-J core rows (rows row0+12, row0+13)

    for (int rr = r0; rr < 6; ++rr) {
        const int rlo = 1 + 2 * rr, rhi = 86 - 2 * rr;
        const int qlo = rlo >> 2, qhi = rhi >> 2;
        const int nq = qhi - qlo + 1;
        const int nslab = (rhi - rlo + 1 + 3) >> 2;
        const int nit = nslab * nq;             // <= 484 always

        // ---------------- READ PHASE ----------------
        if (rr == r0) {   // first round: stash old J core rows from LDS
            Jc0 = ld4s(Jl + (row0 + 12) * LDT + tcol);
            Jc1 = ld4s(Jl + (row0 + 13) * LDT + tcol);
        }

        // erode: 4-row slab -> E in registers (rolling 3-row J window)
        float4 Ereg[4];
        int rb = 0, cc = 0, qq = 0;
        const bool active = (tid < nit);
        if (active) {
            int sb = tid / nq;
            qq = qlo + (tid - sb * nq);
            rb = rlo + (sb << 2);
            cc = qq << 2;
            const float* bp = Jl + (rb - 1) * LDT + cc;
            float4 wA = ld4s(bp);           // row rb-1
            float4 wB = ld4s(bp + LDT);     // row rb
            const bool cOOB = (!interior) && ((unsigned)(x0 + cc) >= W);
            #pragma unroll
            for (int j = 0; j < 4; ++j) {
                float4 wC = ld4s(bp + (j + 2) * LDT);   // row rb+j+1
                float lw = __shfl_up(wB.w, 1, 64);
                float rx = __shfl_down(wB.x, 1, 64);
                if (lane == 0 && qq != qlo)  lw = Jl[(rb + j) * LDT + cc - 1];
                if (lane == 63 && qq != qhi) rx = Jl[(rb + j) * LDT + cc + 4];
                if (qq == qlo) lw = FINF;   // tile-edge / creep col: safe
                if (qq == qhi) rx = FINF;   // creep col: safe
                float4 e;
                e.x = fminf(fminf(fminf(wA.x, wC.x), fminf(lw, wB.y)), wB.x);
                e.y = fminf(fminf(fminf(wA.y, wC.y), fminf(wB.x, wB.z)), wB.y);
                e.z = fminf(fminf(fminf(wA.z, wC.z), fminf(wB.y, wB.w)), wB.z);
                e.w = fminf(fminf(fminf(wA.w, wC.w), fminf(wB.z, rx)), wB.w);
                if (!interior) {
                    int gy = y0 + rb + j;
                    if (((unsigned)gy >= H) | cOOB)
                        e = make_float4(FINF, FINF, FINF, FINF);   // minpool pad
                }
                Ereg[j] = e;
                wA = wB; wB = wC;
            }
        }
        __syncthreads();   // all reads of old J complete

        // ---------------- WRITE PHASE (in place) ----------------
        if (active) {
            #pragma unroll
            for (int j = 0; j < 4; ++j)
                if (rb + j <= rhi) st4s(&Jl[(rb + j) * LDT + cc], Ereg[j]);
        }
        __syncthreads();   // E visible to all

        // ------- dilate (3x3 max) + delta + skel, 2-row slab per thread -------
        const bool last = (rr == 5);
        {
            const float* ebase = Jl + (row0 + 11) * LDT + tcol;
            float4 E[4];
            #pragma unroll
            for (int j = 0; j < 4; ++j) E[j] = ld4s(ebase + j * LDT);
            float lwv[4], rxv[4];
            #pragma unroll
            for (int j = 0; j < 4; ++j) {
                lwv[j] = __shfl_up(E[j].w, 1, 64);
                rxv[j] = __shfl_down(E[j].x, 1, 64);
                if (sq == 0)  lwv[j] = (tx == 0) ? -FINF : Jl[(row0 + 11 + j) * LDT + 11];
                if (sq == 15) rxv[j] = (tx == 7) ? -FINF : Jl[(row0 + 11 + j) * LDT + 76];
            }
            float4 hx[4];
            #pragma unroll
            for (int j = 0; j < 4; ++j) {
                hx[j].x = fmaxf(fmaxf(lwv[j], E[j].x), E[j].y);
                hx[j].y = fmaxf(fmaxf(E[j].x, E[j].y), E[j].z);
                hx[j].z = fmaxf(fmaxf(E[j].y, E[j].z), E[j].w);
                hx[j].w = fmaxf(fmaxf(E[j].z, E[j].w), rxv[j]);
            }
            #pragma unroll
            for (int j = 0; j < 2; ++j) {
                int gy = ty * CORE + row0 + j;
                float4 hm = hx[j], hp = hx[j + 2];
                if (!interior) {
                    if (gy == 0)     hm = make_float4(-FINF, -FINF, -FINF, -FINF);
                    if (gy == H - 1) hp = make_float4(-FINF, -FINF, -FINF, -FINF);
                }
                float4 dm;
                dm.x = fmaxf(fmaxf(hm.x, hx[j + 1].x), hp.x);
                dm.y = fmaxf(fmaxf(hm.y, hx[j + 1].y), hp.y);
                dm.z = fmaxf(fmaxf(hm.z, hx[j + 1].z), hp.z);
                dm.w = fmaxf(fmaxf(hm.w, hx[j + 1].w), hp.w);
                float4 Jv = (j == 0) ? Jc0 : Jc1;
                float d0 = fmaxf(Jv.x - dm.x, 0.f);
                float d1 = fmaxf(Jv.y - dm.y, 0.f);
                float d2 = fmaxf(Jv.z - dm.z, 0.f);
                float d3 = fmaxf(Jv.w - dm.w, 0.f);
                sk2[j].x += fmaxf(d0 - sk2[j].x * d0, 0.f);
                sk2[j].y += fmaxf(d1 - sk2[j].y * d1, 0.f);
                sk2[j].z += fmaxf(d2 - sk2[j].z * d2, 0.f);
                sk2[j].w += fmaxf(d3 - sk2[j].w * d3, 0.f);
                if (last) {
                    st4s(Jo + gy * W + gxc, E[j + 1]);   // Jout = erode at core
                    st4s(Sk + gy * W + gxc, sk2[j]);
                }
            }
            Jc0 = E[1];   // new J core rows -> next round's stash
            Jc1 = E[2];
        }
        if (!last) __syncthreads();   // dilate reads done before next overwrite
    }
}

// ---------------------------------------------------------------- endpoints
__global__ __launch_bounds__(256) void endpoint_kernel(
        const float* __restrict__ skel, double* __restrict__ acc) {
    __shared__ float sR[10][520];    // data at cols 4..515, zeros at 3 and 516
    __shared__ float sw[4];
    const int tid = threadIdx.x;
    const int img = blockIdx.x >> 6;
    const int rb = blockIdx.x & 63;
    const int yB = rb << 3;
    const float* Sk = skel + (size_t)img * S;
    for (int i = tid; i < 1280; i += 256) {
        int r = i >> 7, c4 = i & 127;
        int gy = yB - 1 + r;
        float4 v = make_float4(0.f, 0.f, 0.f, 0.f);
        if ((unsigned)gy < H) v = ld4s(Sk + gy * W + (c4 << 2));
        st4s(&sR[r][4 + (c4 << 2)], v);
    }
    if (tid < 10) { sR[tid][3] = 0.f; sR[tid][516] = 0.f; }
    __syncthreads();
    float t = 0.f, syA = 0.f, sxA = 0.f;
    #pragma unroll
    for (int k = 0; k < 4; ++k) {
        int qidx = k * 256 + tid;
        int rrow = qidx >> 7;            // 0..7
        int x = (qidx & 127) << 2;
        int r = 1 + rrow;
        float gy = (float)(yB + rrow);
        const float* Rm = &sR[r - 1][4 + x];
        const float* Rc = &sR[r][4 + x];
        const float* Rp = &sR[r + 1][4 + x];
        float4 bm = ld4s(Rm); float lm = ld4s(Rm - 4).w, rm = ld4s(Rm + 4).x;
        float4 bc = ld4s(Rc); float lc = ld4s(Rc - 4).w, rc = ld4s(Rc + 4).x;
        float4 bp = ld4s(Rp); float lp = ld4s(Rp - 4).w, rp = ld4s(Rp + 4).x;
        float hm0 = lm + bm.x + bm.y, hm1 = bm.x + bm.y + bm.z;
        float hm2 = bm.y + bm.z + bm.w, hm3 = bm.z + bm.w + rm;
        float hc0 = lc + bc.x + bc.y, hc1 = bc.x + bc.y + bc.z;
        float hc2 = bc.y + bc.z + bc.w, hc3 = bc.z + bc.w + rc;
        float hp0 = lp + bp.x + bp.y, hp1 = bp.x + bp.y + bp.z;
        float hp2 = bp.y + bp.z + bp.w, hp3 = bp.z + bp.w + rp;
        float ns0 = hm0 + hc0 + hp0 + 9.f * bc.x;
        float ns1 = hm1 + hc1 + hp1 + 9.f * bc.y;
        float ns2 = hm2 + hc2 + hp2 + 9.f * bc.z;
        float ns3 = hm3 + hc3 + hp3 + 9.f * bc.w;
        float e0 = ns0 - 11.f, e1 = ns1 - 11.f, e2 = ns2 - 11.f, e3 = ns3 - 11.f;
        float ep0 = expf(-e0 * e0) * bc.x;
        float ep1 = expf(-e1 * e1) * bc.y;
        float ep2 = expf(-e2 * e2) * bc.z;
        float ep3 = expf(-e3 * e3) * bc.w;
        float es = ep0 + ep1 + ep2 + ep3;
        t += es;
        syA += gy * es;
        sxA += ep0 * (float)(x + 0) + ep1 * (float)(x + 1)
             + ep2 * (float)(x + 2) + ep3 * (float)(x + 3);
    }
    float v;
    v = blockReduce(t, sw);   if (tid == 0) atomicAdd(&acc[img * 3 + 0], (double)v);
    v = blockReduce(syA, sw); if (tid == 0) atomicAdd(&acc[img * 3 + 1], (double)v);
    v = blockReduce(sxA, sw); if (tid == 0) atomicAdd(&acc[img * 3 + 2], (double)v);
}

// ---------------------------------------------------------------- final scalar
__global__ __launch_bounds__(256) void final_kernel(
        const double* __restrict__ acc, const double* __restrict__ pb,
        float* __restrict__ out) {
    const int tid = threadIdx.x;
    double si = 0.0, sp = 0.0, sy = 0.0;
    for (int i = tid; i < 1024; i += 256) {
        si += pb[i * 3 + 0]; sp += pb[i * 3 + 1]; sy += pb[i * 3 + 2];
    }
    #pragma unroll
    for (int o = 32; o; o >>= 1) {
        si += __shfl_down(si, o, 64);
        sp += __shfl_down(sp, o, 64);
        sy += __shfl_down(sy, o, 64);
    }
    __shared__ double dsw[3][4];
    int lane = tid & 63, wid = tid >> 6;
    if (lane == 0) { dsw[0][wid] = si; dsw[1][wid] = sp; dsw[2][wid] = sy; }
    __syncthreads();
    if (tid == 0) {
        double inter = dsw[0][0] + dsw[0][1] + dsw[0][2] + dsw[0][3];
        double sump  = dsw[1][0] + dsw[1][1] + dsw[1][2] + dsw[1][3];
        double sumy  = dsw[2][0] + dsw[2][1] + dsw[2][2] + dsw[2][3];
        double dsum = 0.0, csum = 0.0;
        for (int b = 0; b < B; ++b) {
            double tp = acc[b * 3 + 0], typ = acc[b * 3 + 1], txp = acc[b * 3 + 2];
            double tt = acc[(B + b) * 3 + 0], tyt = acc[(B + b) * 3 + 1], txt = acc[(B + b) * 3 + 2];
            double ycp = typ / (tp + 1e-8), xcp = txp / (tp + 1e-8);
            double yct = tyt / (tt + 1e-8), xct = txt / (tt + 1e-8);
            double dy = ycp - yct, dx = xcp - xct;
            dsum += sqrt(dy * dy + dx * dx);
            csum += fabs(tp - tt) / (tp + tt + 1e-8);
        }
        double diag = sqrt((double)(H * H + W * W));
        double distance_loss = (dsum / B) / (diag + 1e-8);
        double count_penalty = csum / B;
        double dice = 1.0 - (2.0 * inter + 1.0) / (sumy + sump + 1.0);
        out[0] = (float)(0.85 * dice + 0.15 * (distance_loss + count_penalty));
    }
}

// ---------------------------------------------------------------- launch
extern "C" void kernel_launch(void* const* d_in, const int* in_sizes, int n_in,
                              void* d_out, int out_size, void* d_ws, size_t ws_size,
                              hipStream_t stream) {
    const float* net = (const float*)d_in[0];   // [8,2,512,512] f32
    const int*   yt  = (const int*)d_in[1];     // [8,1,512,512] i32
    float* out = (float*)d_out;

    float* J0   = (float*)d_ws;                       // 16 MB
    float* J1   = J0 + (size_t)NIMG * S;              // 16 MB
    float* skel = J1 + (size_t)NIMG * S;              // 16 MB
    double* acc = (double*)(skel + (size_t)NIMG * S); // 48 doubles
    double* pb  = acc + 48;                           // 1024*3 doubles

    phase1_kernel<<<1024, 256, 0, stream>>>(net, yt, J0, pb, acc);

    // 41 rounds = 6+6+6+6+6+6+5
    skel_fused_kernel<true><<<NIMG * 64, 512, 0, stream>>>(J0, J1, skel, 0);
    float* a = J1; float* b = J0;
    for (int p = 1; p < 7; ++p) {
        int r0 = (p == 6) ? 1 : 0;   // last phase: 5 rounds (rr = 1..5)
        skel_fused_kernel<false><<<NIMG * 64, 512, 0, stream>>>(a, b, skel, r0);
        float* tmp = a; a = b; b = tmp;
    }

    endpoint_kernel<<<NIMG * 64, 256, 0, stream>>>(skel, acc);
    final_kernel<<<1, 256, 0, stream>>>(acc, pb, out);
}

// Round 7
// 347.532 us; speedup vs baseline: 1.3489x; 1.3489x over previous
//
#include <hip/hip_runtime.h>
#include <math.h>

#define W 512
#define H 512
#define S (W * H)        // 262144
#define B 8
#define NIMG 16
#define CORE_Y 128
#define CORE_X 64
#define HALO 12
#define LDT 88           // tile width (cols)
#define TROWS 154        // 128 + 2*12 + 2 (rows 0..153; all windows in-range)
#define NQ 22            // quads per tile row
#define FINF __builtin_huge_valf()

__device__ __forceinline__ float4 ld4s(const float* p) { return *(const float4*)p; }
__device__ __forceinline__ void st4s(float* p, float4 v) { *(float4*)p = v; }

// block-wide float sum over 256 threads; result valid in thread 0.
__device__ __forceinline__ float blockReduce(float v, float* sw) {
    #pragma unroll
    for (int o = 32; o; o >>= 1) v += __shfl_down(v, o, 64);
    int lane = threadIdx.x & 63, wid = threadIdx.x >> 6;
    if (lane == 0) sw[wid] = v;
    __syncthreads();
    float r = (threadIdx.x < 4) ? sw[threadIdx.x] : 0.f;
    if (wid == 0) { r += __shfl_down(r, 2, 64); r += __shfl_down(r, 1, 64); }
    __syncthreads();
    return r;
}

// ---------------------------------------------------------------- phase 1
// softmax fg prob + y cast -> J0; dice partials -> pb; block 0 zeros acc.
__global__ __launch_bounds__(256) void phase1_kernel(
        const float* __restrict__ net, const int* __restrict__ yt,
        float* __restrict__ J0, double* __restrict__ pb,
        double* __restrict__ acc) {
    __shared__ float sw[4];
    const int tid = threadIdx.x;
    if (blockIdx.x == 0 && tid < 48) acc[tid] = 0.0;   // endpoint accumulators
    float inter = 0.f, sp = 0.f, sy = 0.f;
    for (int i = blockIdx.x * 256 + tid; i < B * S / 4; i += 1024 * 256) {
        int b = i >> 16;               // S/4 = 65536 quads per image
        int s = (i & 65535) << 2;
        const float* nb = net + (size_t)b * 2 * S;
        float4 x0 = ld4s(nb + s);
        float4 x1 = ld4s(nb + S + s);
        int4 yv = *(const int4*)(yt + (size_t)b * S + s);
        float4 p, yf;
        p.x = 1.f / (1.f + expf(x0.x - x1.x));
        p.y = 1.f / (1.f + expf(x0.y - x1.y));
        p.z = 1.f / (1.f + expf(x0.z - x1.z));
        p.w = 1.f / (1.f + expf(x0.w - x1.w));
        yf.x = (float)yv.x; yf.y = (float)yv.y; yf.z = (float)yv.z; yf.w = (float)yv.w;
        st4s(J0 + (size_t)b * S + s, p);
        st4s(J0 + (size_t)(B + b) * S + s, yf);
        inter += p.x * yf.x + p.y * yf.y + p.z * yf.z + p.w * yf.w;
        sp += p.x + p.y + p.z + p.w;
        sy += yf.x + yf.y + yf.z + yf.w;
    }
    float v;
    v = blockReduce(inter, sw); if (tid == 0) pb[blockIdx.x * 3 + 0] = (double)v;
    v = blockReduce(sp, sw);    if (tid == 0) pb[blockIdx.x * 3 + 1] = (double)v;
    v = blockReduce(sy, sw);    if (tid == 0) pb[blockIdx.x * 3 + 2] = (double)v;
}

// ---------------------------------------------------------------- fused skeleton
// T=6 rounds/launch, 128x64 core, 154x88 in-place LDS tile (54.2 KB) ->
// 512 blocks total, exactly 2 resident/CU (LDS-limited), ZERO block tail.
// launch_bounds(512,4): VGPR cap 128 -> no spill (r6's 64-cap spilled 150MB).
// erode: 4-row x 1-quad slabs, 2 sweeps (nit<=836), E in regs across barrier.
// dilate: 4-row x 1-quad slab/thread, skel + old-J carry in registers.
template <bool INIT>
__global__ __launch_bounds__(512, 4) void skel_fused_kernel(
        const float* __restrict__ Jin, float* __restrict__ Jout,
        float* __restrict__ skel, int r0) {
    __shared__ float Jl[TROWS * LDT];   // 154 x 88 floats = 54208 B
    const int tid = threadIdx.x;
    const int lane = tid & 63;
    const int img = blockIdx.x >> 5;
    const int t32 = blockIdx.x & 31;
    const int ty = t32 >> 3, tx = t32 & 7;          // ty 0..3, tx 0..7
    const int y0 = ty * CORE_Y - HALO, x0 = tx * CORE_X - HALO;
    const float* Ji = Jin + (size_t)img * S;
    float* Jo = Jout + (size_t)img * S;
    float* Sk = skel + (size_t)img * S;
    const bool interior = (ty > 0) & (ty < 3) & (tx > 0) & (tx < 7);

    // ---- load 154x88 J tile (quads all-in/out in x: x0 % 4 == 0)
    if (interior) {
        for (int i = tid; i < TROWS * NQ; i += 512) {
            int r = i / NQ, q = i - (i / NQ) * NQ;
            st4s(&Jl[r * LDT + (q << 2)],
                 ld4s(Ji + (y0 + r) * W + x0 + (q << 2)));
        }
    } else {
        for (int i = tid; i < TROWS * NQ; i += 512) {
            int r = i / NQ, q = i - (i / NQ) * NQ;
            int gy = y0 + r, gx = x0 + (q << 2);
            float4 v;
            if ((unsigned)gy < H && (unsigned)gx < W) v = ld4s(Ji + gy * W + gx);
            else v = make_float4(FINF, FINF, FINF, FINF);
            st4s(&Jl[r * LDT + (q << 2)], v);
        }
    }

    // ---- thread = (sq, ss): core rows 4ss..4ss+3, core quad col sq
    const int sq = tid & 15, ss = tid >> 4;     // sq 0..15, ss 0..31
    const int tcol = HALO + (sq << 2);          // tile col of core quad
    const int gxc = tx * CORE_X + (sq << 2);    // global col of core quad
    const int trow = HALO + (ss << 2);          // tile row of slab start
    const int grow = ty * CORE_Y + (ss << 2);   // global row of slab start
    float4 sk4[4];
    #pragma unroll
    for (int j = 0; j < 4; ++j) {
        if (INIT) sk4[j] = make_float4(0.f, 0.f, 0.f, 0.f);
        else      sk4[j] = ld4s(Sk + (grow + j) * W + gxc);
    }
    __syncthreads();

    // carried old-J core rows (tile rows trow..trow+3)
    float4 Jc[4];
    #pragma unroll
    for (int j = 0; j < 4; ++j) Jc[j] = ld4s(Jl + (trow + j) * LDT + tcol);

    for (int rr = r0; rr < 6; ++rr) {
        const int rlo = 1 + 2 * rr;                 // rows [rlo, 152-2rr]
        const int clo = 1 + 2 * rr, chi = 86 - 2 * rr;
        const int qlo = clo >> 2, qhi = chi >> 2;
        const int nq = qhi - qlo + 1;
        const int nslab = (152 - 4 * rr) >> 2;      // exact division, all rr
        const int nit = nslab * nq;                 // 594..836 -> 2 sweeps

        // ---------------- READ PHASE: erode into registers ----------------
        float4 Er[2][4];
        int rb_[2], cc_[2];
        bool act_[2];
        #pragma unroll
        for (int s2 = 0; s2 < 2; ++s2) {
            int it = tid + (s2 << 9);
            const bool act = (it < nit);
            act_[s2] = act;
            if (act) {
                int sb = it / nq;
                int qq = qlo + (it - sb * nq);
                int rb = rlo + (sb << 2);
                int cc = qq << 2;
                rb_[s2] = rb; cc_[s2] = cc;
                const float* bp = Jl + (rb - 1) * LDT + cc;
                float4 wA = ld4s(bp);           // row rb-1
                float4 wB = ld4s(bp + LDT);     // row rb
                const bool cOOB = (!interior) && ((unsigned)(x0 + cc) >= W);
                #pragma unroll
                for (int j = 0; j < 4; ++j) {
                    float4 wC = ld4s(bp + (j + 2) * LDT);   // row rb+j+1
                    float lw = __shfl_up(wB.w, 1, 64);
                    float rx = __shfl_down(wB.x, 1, 64);
                    if (lane == 0 && qq != qlo)  lw = Jl[(rb + j) * LDT + cc - 1];
                    if (lane == 63 && qq != qhi) rx = Jl[(rb + j) * LDT + cc + 4];
                    if (qq == qlo) lw = FINF;   // tile-edge / creep col: safe
                    if (qq == qhi) rx = FINF;   // creep col: safe
                    float4 e;
                    e.x = fminf(fminf(fminf(wA.x, wC.x), fminf(lw, wB.y)), wB.x);
                    e.y = fminf(fminf(fminf(wA.y, wC.y), fminf(wB.x, wB.z)), wB.y);
                    e.z = fminf(fminf(fminf(wA.z, wC.z), fminf(wB.y, wB.w)), wB.z);
                    e.w = fminf(fminf(fminf(wA.w, wC.w), fminf(wB.z, rx)), wB.w);
                    if (!interior) {
                        int gy = y0 + rb + j;
                        if (((unsigned)gy >= H) | cOOB)
                            e = make_float4(FINF, FINF, FINF, FINF);   // minpool pad
                    }
                    Er[s2][j] = e;
                    wA = wB; wB = wC;
                }
            }
        }
        __syncthreads();   // all reads of old J complete

        // ---------------- WRITE PHASE (in place) ----------------
        #pragma unroll
        for (int s2 = 0; s2 < 2; ++s2) {
            if (act_[s2]) {
                #pragma unroll
                for (int j = 0; j < 4; ++j)
                    st4s(&Jl[(rb_[s2] + j) * LDT + cc_[s2]], Er[s2][j]);
            }
        }
        __syncthreads();   // E visible to all

        // ------- dilate (3x3 max) + delta + skel, 4-row slab per thread -------
        const bool last = (rr == 5);
        {
            const float* ebase = Jl + (trow - 1) * LDT + tcol;
            float4 E[6];
            #pragma unroll
            for (int j = 0; j < 6; ++j) E[j] = ld4s(ebase + j * LDT);
            float lwv[6], rxv[6];
            #pragma unroll
            for (int j = 0; j < 6; ++j) {
                lwv[j] = __shfl_up(E[j].w, 1, 64);
                rxv[j] = __shfl_down(E[j].x, 1, 64);
                if (sq == 0)  lwv[j] = (tx == 0) ? -FINF : Jl[(trow - 1 + j) * LDT + 11];
                if (sq == 15) rxv[j] = (tx == 7) ? -FINF : Jl[(trow - 1 + j) * LDT + 76];
            }
            float4 hx[6];
            #pragma unroll
            for (int j = 0; j < 6; ++j) {
                hx[j].x = fmaxf(fmaxf(lwv[j], E[j].x), E[j].y);
                hx[j].y = fmaxf(fmaxf(E[j].x, E[j].y), E[j].z);
                hx[j].z = fmaxf(fmaxf(E[j].y, E[j].z), E[j].w);
                hx[j].w = fmaxf(fmaxf(E[j].z, E[j].w), rxv[j]);
            }
            #pragma unroll
            for (int j = 0; j < 4; ++j) {
                int gy = grow + j;
                float4 hm = hx[j], hp = hx[j + 2];
                if (!interior) {
                    if (gy == 0)     hm = make_float4(-FINF, -FINF, -FINF, -FINF);
                    if (gy == H - 1) hp = make_float4(-FINF, -FINF, -FINF, -FINF);
                }
                float4 dm;
                dm.x = fmaxf(fmaxf(hm.x, hx[j + 1].x), hp.x);
                dm.y = fmaxf(fmaxf(hm.y, hx[j + 1].y), hp.y);
                dm.z = fmaxf(fmaxf(hm.z, hx[j + 1].z), hp.z);
                dm.w = fmaxf(fmaxf(hm.w, hx[j + 1].w), hp.w);
                float4 Jv = Jc[j];
                float d0 = fmaxf(Jv.x - dm.x, 0.f);
                float d1 = fmaxf(Jv.y - dm.y, 0.f);
                float d2 = fmaxf(Jv.z - dm.z, 0.f);
                float d3 = fmaxf(Jv.w - dm.w, 0.f);
                sk4[j].x += fmaxf(d0 - sk4[j].x * d0, 0.f);
                sk4[j].y += fmaxf(d1 - sk4[j].y * d1, 0.f);
                sk4[j].z += fmaxf(d2 - sk4[j].z * d2, 0.f);
                sk4[j].w += fmaxf(d3 - sk4[j].w * d3, 0.f);
                Jc[j] = E[j + 1];   // new J core row -> next round's stash
                if (last) {
                    st4s(Jo + gy * W + gxc, E[j + 1]);   // Jout = erode at core
                    st4s(Sk + gy * W + gxc, sk4[j]);
                }
            }
        }
        if (!last) __syncthreads();   // dilate reads done before next overwrite
    }
}

// ---------------------------------------------------------------- endpoints
__global__ __launch_bounds__(256) void endpoint_kernel(
        const float* __restrict__ skel, double* __restrict__ acc) {
    __shared__ float sR[10][520];    // data at cols 4..515, zeros at 3 and 516
    __shared__ float sw[4];
    const int tid = threadIdx.x;
    const int img = blockIdx.x >> 6;
    const int rb = blockIdx.x & 63;
    const int yB = rb << 3;
    const float* Sk = skel + (size_t)img * S;
    for (int i = tid; i < 1280; i += 256) {
        int r = i >> 7, c4 = i & 127;
        int gy = yB - 1 + r;
        float4 v = make_float4(0.f, 0.f, 0.f, 0.f);
        if ((unsigned)gy < H) v = ld4s(Sk + gy * W + (c4 << 2));
        st4s(&sR[r][4 + (c4 << 2)], v);
    }
    if (tid < 10) { sR[tid][3] = 0.f; sR[tid][516] = 0.f; }
    __syncthreads();
    float t = 0.f, syA = 0.f, sxA = 0.f;
    #pragma unroll
    for (int k = 0; k < 4; ++k) {
        int qidx = k * 256 + tid;
        int rrow = qidx >> 7;            // 0..7
        int x = (qidx & 127) << 2;
        int r = 1 + rrow;
        float gy = (float)(yB + rrow);
        const float* Rm = &sR[r - 1][4 + x];
        const float* Rc = &sR[r][4 + x];
        const float* Rp = &sR[r + 1][4 + x];
        float4 bm = ld4s(Rm); float lm = ld4s(Rm - 4).w, rm = ld4s(Rm + 4).x;
        float4 bc = ld4s(Rc); float lc = ld4s(Rc - 4).w, rc = ld4s(Rc + 4).x;
        float4 bp = ld4s(Rp); float lp = ld4s(Rp - 4).w, rp = ld4s(Rp + 4).x;
        float hm0 = lm + bm.x + bm.y, hm1 = bm.x + bm.y + bm.z;
        float hm2 = bm.y + bm.z + bm.w, hm3 = bm.z + bm.w + rm;
        float hc0 = lc + bc.x + bc.y, hc1 = bc.x + bc.y + bc.z;
        float hc2 = bc.y + bc.z + bc.w, hc3 = bc.z + bc.w + rc;
        float hp0 = lp + bp.x + bp.y, hp1 = bp.x + bp.y + bp.z;
        float hp2 = bp.y + bp.z + bp.w, hp3 = bp.z + bp.w + rp;
        float ns0 = hm0 + hc0 + hp0 + 9.f * bc.x;
        float ns1 = hm1 + hc1 + hp1 + 9.f * bc.y;
        float ns2 = hm2 + hc2 + hp2 + 9.f * bc.z;
        float ns3 = hm3 + hc3 + hp3 + 9.f * bc.w;
        float e0 = ns0 - 11.f, e1 = ns1 - 11.f, e2 = ns2 - 11.f, e3 = ns3 - 11.f;
        float ep0 = expf(-e0 * e0) * bc.x;
        float ep1 = expf(-e1 * e1) * bc.y;
        float ep2 = expf(-e2 * e2) * bc.z;
        float ep3 = expf(-e3 * e3) * bc.w;
        float es = ep0 + ep1 + ep2 + ep3;
        t += es;
        syA += gy * es;
        sxA += ep0 * (float)(x + 0) + ep1 * (float)(x + 1)
             + ep2 * (float)(x + 2) + ep3 * (float)(x + 3);
    }
    float v;
    v = blockReduce(t, sw);   if (tid == 0) atomicAdd(&acc[img * 3 + 0], (double)v);
    v = blockReduce(syA, sw); if (tid == 0) atomicAdd(&acc[img * 3 + 1], (double)v);
    v = blockReduce(sxA, sw); if (tid == 0) atomicAdd(&acc[img * 3 + 2], (double)v);
}

// ---------------------------------------------------------------- final scalar
__global__ __launch_bounds__(256) void final_kernel(
        const double* __restrict__ acc, const double* __restrict__ pb,
        float* __restrict__ out) {
    const int tid = threadIdx.x;
    double si = 0.0, sp = 0.0, sy = 0.0;
    for (int i = tid; i < 1024; i += 256) {
        si += pb[i * 3 + 0]; sp += pb[i * 3 + 1]; sy += pb[i * 3 + 2];
    }
    #pragma unroll
    for (int o = 32; o; o >>= 1) {
        si += __shfl_down(si, o, 64);
        sp += __shfl_down(sp, o, 64);
        sy += __shfl_down(sy, o, 64);
    }
    __shared__ double dsw[3][4];
    int lane = tid & 63, wid = tid >> 6;
    if (lane == 0) { dsw[0][wid] = si; dsw[1][wid] = sp; dsw[2][wid] = sy; }
    __syncthreads();
    if (tid == 0) {
        double inter = dsw[0][0] + dsw[0][1] + dsw[0][2] + dsw[0][3];
        double sump  = dsw[1][0] + dsw[1][1] + dsw[1][2] + dsw[1][3];
        double sumy  = dsw[2][0] + dsw[2][1] + dsw[2][2] + dsw[2][3];
        double dsum = 0.0, csum = 0.0;
        for (int b = 0; b < B; ++b) {
            double tp = acc[b * 3 + 0], typ = acc[b * 3 + 1], txp = acc[b * 3 + 2];
            double tt = acc[(B + b) * 3 + 0], tyt = acc[(B + b) * 3 + 1], txt = acc[(B + b) * 3 + 2];
            double ycp = typ / (tp + 1e-8), xcp = txp / (tp + 1e-8);
            double yct = tyt / (tt + 1e-8), xct = txt / (tt + 1e-8);
            double dy = ycp - yct, dx = xcp - xct;
            dsum += sqrt(dy * dy + dx * dx);
            csum += fabs(tp - tt) / (tp + tt + 1e-8);
        }
        double diag = sqrt((double)(H * H + W * W));
        double distance_loss = (dsum / B) / (diag + 1e-8);
        double count_penalty = csum / B;
        double dice = 1.0 - (2.0 * inter + 1.0) / (sumy + sump + 1.0);
        out[0] = (float)(0.85 * dice + 0.15 * (distance_loss + count_penalty));
    }
}

// ---------------------------------------------------------------- launch
extern "C" void kernel_launch(void* const* d_in, const int* in_sizes, int n_in,
                              void* d_out, int out_size, void* d_ws, size_t ws_size,
                              hipStream_t stream) {
    const float* net = (const float*)d_in[0];   // [8,2,512,512] f32
    const int*   yt  = (const int*)d_in[1];     // [8,1,512,512] i32
    float* out = (float*)d_out;

    float* J0   = (float*)d_ws;                       // 16 MB
    float* J1   = J0 + (size_t)NIMG * S;              // 16 MB
    float* skel = J1 + (size_t)NIMG * S;              // 16 MB
    double* acc = (double*)(skel + (size_t)NIMG * S); // 48 doubles
    double* pb  = acc + 48;                           // 1024*3 doubles

    phase1_kernel<<<1024, 256, 0, stream>>>(net, yt, J0, pb, acc);

    // 41 rounds = 6+6+6+6+6+6+5
    skel_fused_kernel<true><<<NIMG * 32, 512, 0, stream>>>(J0, J1, skel, 0);
    float* a = J1; float* b = J0;
    for (int p = 1; p < 7; ++p) {
        int r0 = (p == 6) ? 1 : 0;   // last phase: 5 rounds (rr = 1..5)
        skel_fused_kernel<false><<<NIMG * 32, 512, 0, stream>>>(a, b, skel, r0);
        float* tmp = a; a = b; b = tmp;
    }

    endpoint_kernel<<<NIMG * 64, 256, 0, stream>>>(skel, acc);
    final_kernel<<<1, 256, 0, stream>>>(acc, pb, out);
}